// Round 4
// baseline (163.447 us; speedup 1.0000x reference)
//
#include <hip/hip_runtime.h>

#define NPAIR 10
#define NTRI  10

constexpr int c_i1[NTRI]  = {0,0,1,0,1,2,4,4,5,7};
constexpr int c_i2[NTRI]  = {4,5,7,6,8,9,7,8,9,9};
constexpr int c_i12[NTRI] = {1,2,2,3,3,3,5,6,6,8};

typedef float vf4 __attribute__((ext_vector_type(4)));

__global__ __launch_bounds__(256) void accum_loss_kernel(
    const float* __restrict__ rotas,   // [NPAIR][B][3][3]
    const float* __restrict__ transs,  // [NPAIR][B][3]
    float* __restrict__ block_sums,    // [gridDim.x]
    int B)
{
    const int b = blockIdx.x * 256 + threadIdx.x;

    float R[NPAIR][9];
    float t[NPAIR][3];

    // Wide direct loads on the natural record layout: 9-float R record as
    // dwordx4 + dwordx4 + dword (gfx9 global loads need only dword alignment;
    // stride 36 B is 4-aligned), 3-float t record as dwordx3.
    // 40 independent load instructions/thread, no LDS, no fences. Wave spans
    // a contiguous 2304 B region per pair -> every fetched line fully used.
#pragma unroll
    for (int p = 0; p < NPAIR; ++p) {
        const float* rp = rotas + ((size_t)p * B + b) * 9;
        vf4 a, c;
        float e;
        __builtin_memcpy(&a, rp,     16);   // global_load_dwordx4 (align 4)
        __builtin_memcpy(&c, rp + 4, 16);   // global_load_dwordx4
        e = rp[8];                          // global_load_dword
        R[p][0] = a.x; R[p][1] = a.y; R[p][2] = a.z; R[p][3] = a.w;
        R[p][4] = c.x; R[p][5] = c.y; R[p][6] = c.z; R[p][7] = c.w;
        R[p][8] = e;

        const float* tp = transs + ((size_t)p * B + b) * 3;
        __builtin_memcpy(&t[p][0], tp, 12); // global_load_dwordx3
    }

    float rl = 0.0f, tl = 0.0f;
#pragma unroll
    for (int tr = 0; tr < NTRI; ++tr) {
        const float* R1  = R[c_i1[tr]];
        const float* R2  = R[c_i2[tr]];
        const float* R12 = R[c_i12[tr]];
        const float* t1  = t[c_i1[tr]];
        const float* t2  = t[c_i2[tr]];
        const float* t12 = t[c_i12[tr]];
#pragma unroll
        for (int i = 0; i < 3; ++i) {
#pragma unroll
            for (int j = 0; j < 3; ++j) {
                float f = fmaf(R1[i*3+0], R2[0*3+j],
                          fmaf(R1[i*3+1], R2[1*3+j],
                               R1[i*3+2] * R2[2*3+j]));
                float d = f - R12[i*3+j];
                rl = fmaf(d, d, rl);
            }
            float ft = fmaf(R1[i*3+0], t1[0],
                       fmaf(R1[i*3+1], t1[1],
                            R1[i*3+2] * t1[2])) + t2[i];
            float dt = ft - t12[i];
            tl = fmaf(dt, dt, tl);
        }
    }
    float loss = fmaf(rl, 50.0f, tl);

    // wave (64-lane) reduction
#pragma unroll
    for (int off = 32; off >= 1; off >>= 1)
        loss += __shfl_down(loss, off, 64);

    __shared__ float ws[4];
    const int lane = threadIdx.x & 63;
    const int wave = threadIdx.x >> 6;
    if (lane == 0) ws[wave] = loss;
    __syncthreads();
    if (threadIdx.x == 0)
        block_sums[blockIdx.x] = ws[0] + ws[1] + ws[2] + ws[3];
}

__global__ __launch_bounds__(256) void final_reduce_kernel(
    const float* __restrict__ block_sums, float* __restrict__ out, int n)
{
    float s = 0.0f;
    for (int i = threadIdx.x; i < n; i += blockDim.x) s += block_sums[i];
#pragma unroll
    for (int off = 32; off >= 1; off >>= 1)
        s += __shfl_down(s, off, 64);

    __shared__ float ws[4];
    const int lane = threadIdx.x & 63;
    const int wid  = threadIdx.x >> 6;
    if (lane == 0) ws[wid] = s;
    __syncthreads();
    if (threadIdx.x == 0)
        out[0] = ws[0] + ws[1] + ws[2] + ws[3];
}

extern "C" void kernel_launch(void* const* d_in, const int* in_sizes, int n_in,
                              void* d_out, int out_size, void* d_ws, size_t ws_size,
                              hipStream_t stream)
{
    const float* rotas  = (const float*)d_in[0];
    const float* transs = (const float*)d_in[1];
    float* out = (float*)d_out;

    const int B = in_sizes[0] / (NPAIR * 9);   // 262144
    const int threads = 256;
    const int blocks  = B / threads;           // 1024

    float* block_sums = (float*)d_ws;

    accum_loss_kernel<<<blocks, threads, 0, stream>>>(rotas, transs, block_sums, B);
    final_reduce_kernel<<<1, threads, 0, stream>>>(block_sums, out, blocks);
}

// Round 5
// 162.021 us; speedup vs baseline: 1.0088x; 1.0088x over previous
//
#include <hip/hip_runtime.h>

#define NPAIR 10
#define NTRI  10

constexpr int c_i1[NTRI]  = {0,0,1,0,1,2,4,4,5,7};
constexpr int c_i2[NTRI]  = {4,5,7,6,8,9,7,8,9,9};
constexpr int c_i12[NTRI] = {1,2,2,3,3,3,5,6,6,8};

typedef float vf4 __attribute__((ext_vector_type(4)));

__global__ __launch_bounds__(256) void accum_loss_kernel(
    const float* __restrict__ rotas,   // [NPAIR][B][3][3]
    const float* __restrict__ transs,  // [NPAIR][B][3]
    float* __restrict__ out,           // [1], pre-zeroed via hipMemsetAsync
    int B)
{
    const int b = blockIdx.x * 256 + threadIdx.x;

    float R[NPAIR][9];
    float t[NPAIR][3];

    // Wide direct loads on the natural record layout: 9-float R record as
    // dwordx4 + dwordx4 + dword (global loads need only dword alignment),
    // 3-float t record as dwordx3. 40 independent loads/thread, no LDS
    // staging, no fences. Wave spans a contiguous 2304 B region per pair.
#pragma unroll
    for (int p = 0; p < NPAIR; ++p) {
        const float* rp = rotas + ((size_t)p * B + b) * 9;
        vf4 a, c;
        float e;
        __builtin_memcpy(&a, rp,     16);
        __builtin_memcpy(&c, rp + 4, 16);
        e = rp[8];
        R[p][0] = a.x; R[p][1] = a.y; R[p][2] = a.z; R[p][3] = a.w;
        R[p][4] = c.x; R[p][5] = c.y; R[p][6] = c.z; R[p][7] = c.w;
        R[p][8] = e;

        const float* tp = transs + ((size_t)p * B + b) * 3;
        __builtin_memcpy(&t[p][0], tp, 12);
    }

    float rl = 0.0f, tl = 0.0f;
#pragma unroll
    for (int tr = 0; tr < NTRI; ++tr) {
        const float* R1  = R[c_i1[tr]];
        const float* R2  = R[c_i2[tr]];
        const float* R12 = R[c_i12[tr]];
        const float* t1  = t[c_i1[tr]];
        const float* t2  = t[c_i2[tr]];
        const float* t12 = t[c_i12[tr]];
#pragma unroll
        for (int i = 0; i < 3; ++i) {
#pragma unroll
            for (int j = 0; j < 3; ++j) {
                float f = fmaf(R1[i*3+0], R2[0*3+j],
                          fmaf(R1[i*3+1], R2[1*3+j],
                               R1[i*3+2] * R2[2*3+j]));
                float d = f - R12[i*3+j];
                rl = fmaf(d, d, rl);
            }
            float ft = fmaf(R1[i*3+0], t1[0],
                       fmaf(R1[i*3+1], t1[1],
                            R1[i*3+2] * t1[2])) + t2[i];
            float dt = ft - t12[i];
            tl = fmaf(dt, dt, tl);
        }
    }
    float loss = fmaf(rl, 50.0f, tl);

    // wave (64-lane) reduction
#pragma unroll
    for (int off = 32; off >= 1; off >>= 1)
        loss += __shfl_down(loss, off, 64);

    __shared__ float ws[4];
    const int lane = threadIdx.x & 63;
    const int wave = threadIdx.x >> 6;
    if (lane == 0) ws[wave] = loss;
    __syncthreads();
    // one device-scope atomic per block (1024 total): fuses the final
    // reduction, removing the second launch + inter-kernel gap.
    if (threadIdx.x == 0)
        atomicAdd(out, ws[0] + ws[1] + ws[2] + ws[3]);
}

extern "C" void kernel_launch(void* const* d_in, const int* in_sizes, int n_in,
                              void* d_out, int out_size, void* d_ws, size_t ws_size,
                              hipStream_t stream)
{
    const float* rotas  = (const float*)d_in[0];
    const float* transs = (const float*)d_in[1];
    float* out = (float*)d_out;

    const int B = in_sizes[0] / (NPAIR * 9);   // 262144
    const int threads = 256;
    const int blocks  = B / threads;           // 1024

    // d_out is poisoned 0xAA before every timed launch; zero it ourselves.
    hipMemsetAsync(out, 0, sizeof(float), stream);
    accum_loss_kernel<<<blocks, threads, 0, stream>>>(rotas, transs, out, B);
}